// Round 9
// baseline (152.863 us; speedup 1.0000x reference)
//
#include <hip/hip_runtime.h>
#include <math.h>

// CMCV3Loss: B=512, S=8, D=128, H=64. Inputs: 4 x (4096x128 fp32), seq_len.
// bf16-MFMA symmetric grams; loss_row = lse_{m!=n} - pos. Fixed max-shift:
// ex = exp((s-1)*INV_T) = exp2(fma(s, C1EXP, -C1EXP)) since s<=1 for normalized vecs.
// 3 launches: k_prep, k_gram, k_tail.
// R9: k_gram loads MFMA fragments DIRECTLY from global (each frag = contiguous
// 16B of a row -> one global_load_dwordx4). No LDS, no barriers in the K-loop —
// removes the stage-serialized vmcnt(0)+barrier stalls (~60% of R8's cycles).
// 2x read redundancy served by L2/L3 (~350MB @ 34.5TB/s ~ 10us, overlapped).
//
// ws float offsets:
#define CTR_L1 0        // 8 counters, stride 32 floats (k_tail arrival)
#define CTR_L2 2048     // single second-level counter
#define RS_T   49152    // temporal rowsums [4][4096]
#define RS_C   65536    // contrastive rowsums [4 calls][8 p][1024]
#define SLOT   98304    // slots stride 32: 0..7 c-log, 8..15 t-log, 16..23 ortho, 24 posC, 25 posT
// ws byte offsets (bf16 arrays):
#define ZF_BYTE 397312   // znfull bf16 [4][4096][128]
#define ZH_BYTE 4591616  // znhalf bf16 [4][4096][128] (cols 0..63 sh-normed, 64..127 pv-normed)

#define INV_T 14.285714285714286f
#define C1EXP 20.609929155556627f   // INV_T * log2(e)
#define EPS_N 1e-8f
#define NBLK_TAIL 192                // 8 groups x 24

typedef __attribute__((ext_vector_type(8))) short short8;
typedef __attribute__((ext_vector_type(4))) float floatx4;

__device__ __forceinline__ const float* pick4(const float* a, const float* b,
                                              const float* c, const float* d, int i) {
    return i == 0 ? a : i == 1 ? b : i == 2 ? c : d;
}

__device__ __forceinline__ unsigned short f2bf(float x) {
    unsigned u = __float_as_uint(x);
    u += 0x7fff + ((u >> 16) & 1);
    return (unsigned short)(u >> 16);
}

// ---------- prep: zero counters+RS region, per-sequence norms, bf16 convert, ortho/pos dots ----------
// grid 512 (one per sequence), block 256.
__global__ __launch_bounds__(256) void k_prep(const float* __restrict__ in0, const float* __restrict__ in1,
                                              const float* __restrict__ in2, const float* __restrict__ in3,
                                              float* __restrict__ ws) {
    __shared__ float buf[4][8][128];    // 4 inputs x 8 rows of this sequence
    __shared__ float iv[3][32];         // [sh,pv,full] inverse norms, idx = input*8+row
    __shared__ float red[3];
    const int s = blockIdx.x;
    const int tid = threadIdx.x;

    int gid = s * 256 + tid;
    if (gid < 2080) ws[gid] = 0.0f;                 // arrival counters (L1 + L2)
    if (gid < 50176) ws[RS_T + gid] = 0.0f;         // rowsums + slots
    if (tid < 3) red[tid] = 0.0f;

    #pragma unroll
    for (int i = 0; i < 4; i++) {
        int e4 = tid + i * 256;
        int inp = e4 >> 8, row = (e4 >> 5) & 7, c4 = e4 & 31;
        float4 f = *(const float4*)(pick4(in0, in1, in2, in3, inp) + (size_t)(s * 8 + row) * 128 + c4 * 4);
        *(float4*)(&buf[inp][row][c4 * 4]) = f;
    }
    __syncthreads();

    // norms: thread = (row32 = tid>>3) x (seg = tid&7), 16 els each; segs 0..3 = sh half
    {
        int row32 = tid >> 3, seg = tid & 7;
        const float* rp_ = &buf[row32 >> 3][row32 & 7][seg * 16];
        float ss = 0.0f;
        #pragma unroll
        for (int k = 0; k < 4; k++) {
            float4 x = *(const float4*)(rp_ + k * 4);
            ss = fmaf(x.x, x.x, fmaf(x.y, x.y, fmaf(x.z, x.z, fmaf(x.w, x.w, ss))));
        }
        ss += __shfl_xor(ss, 1); ss += __shfl_xor(ss, 2);   // sum own half
        float cross = __shfl_xor(ss, 4);                    // other half
        if (seg == 0) {
            iv[0][row32] = 1.0f / fmaxf(sqrtf(ss), EPS_N);          // sh
            iv[2][row32] = 1.0f / fmaxf(sqrtf(ss + cross), EPS_N);  // full
        }
        if (seg == 4) iv[1][row32] = 1.0f / fmaxf(sqrtf(ss), EPS_N); // pv
    }
    __syncthreads();

    // convert: thread = input(t>>6) x row((t>>3)&7) x 16-col chunk ((t&7)*16)
    {
        int input = tid >> 6, row = (tid >> 3) & 7, cs = (tid & 7) * 16;
        float scF = iv[2][input * 8 + row];
        float scH = iv[cs < 64 ? 0 : 1][input * 8 + row];
        unsigned short* zf = (unsigned short*)((char*)ws + ZF_BYTE) + (size_t)input * 524288 + (size_t)(s * 8 + row) * 128 + cs;
        unsigned short* zh = (unsigned short*)((char*)ws + ZH_BYTE) + (size_t)input * 524288 + (size_t)(s * 8 + row) * 128 + cs;
        const float* bp = &buf[input][row][cs];
        #pragma unroll
        for (int k4 = 0; k4 < 4; k4++) {
            float4 x = *(const float4*)(bp + k4 * 4);
            ushort4 of, oh;
            of.x = f2bf(x.x * scF); of.y = f2bf(x.y * scF); of.z = f2bf(x.z * scF); of.w = f2bf(x.w * scF);
            oh.x = f2bf(x.x * scH); oh.y = f2bf(x.y * scH); oh.z = f2bf(x.z * scH); oh.w = f2bf(x.w * scH);
            *(ushort4*)(zf + k4 * 4) = of;
            *(ushort4*)(zh + k4 * 4) = oh;
        }
    }

    // small dots: ortho (tid<48), contrastive pos (48..79), temporal pos (80..135)
    float val = 0.0f;
    int cat = -1;
    if (tid < 48) {
        const int oa[6]  = {0, 2, 1, 3, 0, 1};
        const int oaf[6] = {0, 0, 0, 0, 64, 64};
        const int ob[6]  = {0, 2, 1, 3, 2, 3};
        int term = tid >> 3, row = tid & 7;
        const float* A = &buf[oa[term]][row][oaf[term]];
        const float* B = &buf[ob[term]][row][64];
        float d = 0.0f;
        #pragma unroll
        for (int k = 0; k < 16; k++) {
            float4 x = *(const float4*)(A + k * 4);
            float4 y = *(const float4*)(B + k * 4);
            d = fmaf(x.x, y.x, fmaf(x.y, y.y, fmaf(x.z, y.z, fmaf(x.w, y.w, d))));
        }
        float ia = iv[oaf[term] ? 1 : 0][oa[term] * 8 + row];
        float ib = iv[1][ob[term] * 8 + row];
        val = fmaxf(d * ia * ib, 0.0f);
        cat = 2;
    } else if (tid < 80) {
        const int ca[4] = {0, 1, 0, 2}, cb[4] = {2, 3, 1, 3}, coff[4] = {0, 0, 64, 64};
        int call = (tid - 48) >> 3, row = (tid - 48) & 7;
        const float* A = &buf[ca[call]][row][coff[call]];
        const float* B = &buf[cb[call]][row][coff[call]];
        float d = 0.0f;
        #pragma unroll
        for (int k = 0; k < 16; k++) {
            float4 x = *(const float4*)(A + k * 4);
            float4 y = *(const float4*)(B + k * 4);
            d = fmaf(x.x, y.x, fmaf(x.y, y.y, fmaf(x.z, y.z, fmaf(x.w, y.w, d))));
        }
        int ivb = coff[call] ? 1 : 0;
        val = d * iv[ivb][ca[call] * 8 + row] * iv[ivb][cb[call] * 8 + row];
        cat = 0;
    } else if (tid < 136) {
        int u = tid - 80;
        int inp = u / 14, v = u % 14, pp = v >> 1, half = v & 1;
        int ra = (pp == 0) ? 1 : (pp + 1);
        const float* A = &buf[inp][ra][half * 64];
        const float* B = &buf[inp][0][half * 64];
        float d = 0.0f;
        #pragma unroll
        for (int k = 0; k < 16; k++) {
            float4 x = *(const float4*)(A + k * 4);
            float4 y = *(const float4*)(B + k * 4);
            d = fmaf(x.x, y.x, fmaf(x.y, y.y, fmaf(x.z, y.z, fmaf(x.w, y.w, d))));
        }
        float wgt = (pp == 0) ? 2.0f : 1.0f;
        val = d * wgt * iv[2][inp * 8 + ra] * iv[2][inp * 8];
        cat = 1;
    }
    if (cat >= 0) atomicAdd(&red[cat], val);
    __syncthreads();
    if (tid == 0) atomicAdd(ws + SLOT + 32 * 24, red[0]);
    if (tid == 1) atomicAdd(ws + SLOT + 32 * 25, red[1]);
    if (tid == 2) atomicAdd(ws + SLOT + 32 * (16 + (s & 7)), red[2]);
}

// ---------- unified symmetric gram: direct global->VGPR fragment loads, no LDS ----------
// blocks [0,2176) temporal (4 inputs x 544), [2176,3456) contrastive (32 x 40)
// Frag for lane l: row = tilebase + i*16 + (l&15), 16B k-chunk = ((l>>4)&3)*8.
// Lanes l, l+16 read adjacent 16B of the same row -> 16 x 64B segments/load: coalesced enough, L2-resident.
__global__ __launch_bounds__(256) void k_gram(float* __restrict__ ws) {
    const int tid = threadIdx.x;
    const int b = blockIdx.x;

    const short* baseR;
    const short* baseC;
    int rstride, nk;
    float* rsR;
    float* rsC;
    bool diag;

    if (b < 2176) {
        int input = b / 544, t = b % 544;
        int j = t >> 5, i = t & 31;
        if (j == 16 && i >= 16) return;          // folded duplicate
        int rt = i, ct = (i + j) & 31;
        diag = (j == 0);
        const short* zf = (const short*)((const char*)ws + ZF_BYTE) + (size_t)input * 524288;
        baseR = zf + rt * 16384;
        baseC = zf + ct * 16384;
        rstride = 128; nk = 2;
        rsR = ws + RS_T + input * 4096 + rt * 128;
        rsC = ws + RS_T + input * 4096 + ct * 128;
    } else {
        int c = b - 2176;
        int callp = c / 40, t = c % 40;
        int j = t >> 3, i = t & 7;
        if (j == 4 && i >= 4) return;
        int call = callp >> 3, p = callp & 7;
        int rt = i, ct = (i + j) & 7;
        diag = (j == 0);
        const int ca[4] = {0, 1, 0, 2}, cb[4] = {2, 3, 1, 3}, coff[4] = {0, 0, 64, 64};
        const short* zh = (const short*)((const char*)ws + ZH_BYTE);
        int rbase = rt * 128, cbase = ct * 128;
        baseR = zh + (size_t)(rbase < 512 ? ca[call] : cb[call]) * 524288
                   + (size_t)((rbase & 511) * 8 + p) * 128 + coff[call];
        baseC = zh + (size_t)(cbase < 512 ? ca[call] : cb[call]) * 524288
                   + (size_t)((cbase & 511) * 8 + p) * 128 + coff[call];
        rstride = 1024; nk = 1;
        rsR = ws + RS_C + (call * 8 + p) * 1024 + rbase;
        rsC = ws + RS_C + (call * 8 + p) * 1024 + cbase;
    }

    floatx4 acc[4][4];
    #pragma unroll
    for (int ri = 0; ri < 4; ri++)
        #pragma unroll
        for (int ci = 0; ci < 4; ci++) acc[ri][ci] = (floatx4){0.f, 0.f, 0.f, 0.f};

    const int w = tid >> 6, lane = tid & 63, quad = (tid >> 4) & 3, l15 = tid & 15;
    const int wrow = (w >> 1) * 64, wcol = (w & 1) * 64;

    // per-lane fragment base pointers (row part lane-varying, k-chunk via quad)
    const short* aBase = baseR + (size_t)(wrow + l15) * rstride + quad * 8;
    const short* bBase = baseC + (size_t)(wcol + l15) * rstride + quad * 8;

    for (int kh = 0; kh < nk; kh++) {
        const int kbase = kh * 64;
        #pragma unroll
        for (int ks = 0; ks < 2; ks++) {
            const int ko = kbase + ks * 32;
            short8 a[4], bb[4];
            #pragma unroll
            for (int i = 0; i < 4; i++) {
                a[i]  = *(const short8*)(aBase + (size_t)(i * 16) * rstride + ko);
                bb[i] = *(const short8*)(bBase + (size_t)(i * 16) * rstride + ko);
            }
            #pragma unroll
            for (int ri = 0; ri < 4; ri++)
                #pragma unroll
                for (int ci = 0; ci < 4; ci++)
                    acc[ri][ci] = __builtin_amdgcn_mfma_f32_16x16x32_bf16(a[ri], bb[ci], acc[ri][ci], 0, 0, 0);
        }
    }

    if (diag) {
        #pragma unroll
        for (int ri = 0; ri < 4; ri++) {
            #pragma unroll
            for (int reg = 0; reg < 4; reg++) {
                int rloc = wrow + ri * 16 + quad * 4 + reg;
                float rp = 0.f;
                #pragma unroll
                for (int ci = 0; ci < 4; ci++) {
                    int cloc = wcol + ci * 16 + l15;
                    float ex = __builtin_amdgcn_exp2f(fmaf(acc[ri][ci][reg], C1EXP, -C1EXP));
                    rp += (cloc != rloc) ? ex : 0.f;   // exact diag exclusion
                }
                rp += __shfl_xor(rp, 1); rp += __shfl_xor(rp, 2);
                rp += __shfl_xor(rp, 4); rp += __shfl_xor(rp, 8);
                if (l15 == 0) atomicAdd(rsR + rloc, rp);
            }
        }
    } else {
        float colp[4] = {0.f, 0.f, 0.f, 0.f};
        #pragma unroll
        for (int ri = 0; ri < 4; ri++) {
            #pragma unroll
            for (int reg = 0; reg < 4; reg++) {
                int rloc = wrow + ri * 16 + quad * 4 + reg;
                float rp = 0.f;
                #pragma unroll
                for (int ci = 0; ci < 4; ci++) {
                    float ex = __builtin_amdgcn_exp2f(fmaf(acc[ri][ci][reg], C1EXP, -C1EXP));
                    rp += ex;
                    colp[ci] += ex;
                }
                rp += __shfl_xor(rp, 1); rp += __shfl_xor(rp, 2);
                rp += __shfl_xor(rp, 4); rp += __shfl_xor(rp, 8);
                if (l15 == 0) atomicAdd(rsR + rloc, rp);
            }
        }
        #pragma unroll
        for (int ci = 0; ci < 4; ci++) {           // transpose contribution
            colp[ci] += __shfl_xor(colp[ci], 16);
            colp[ci] += __shfl_xor(colp[ci], 32);
            if (lane < 16) atomicAdd(rsC + wcol + ci * 16 + l15, colp[ci]);
        }
    }
}

// ---------- tail: grid-parallel logsum + arrival-gated final ----------
__global__ __launch_bounds__(256) void k_tail(float* __restrict__ ws, float* __restrict__ out) {
    __shared__ float tred[4];
    __shared__ int lastf;
    const int tid = threadIdx.x;
    const int b = blockIdx.x;
    const int idx = b * 256 + tid;       // blocks 0..63 temporal, 64..191 contrastive

    float l = __logf(ws[RS_T + idx]);
    #pragma unroll
    for (int m = 1; m < 64; m <<= 1) l += __shfl_xor(l, m);
    if ((tid & 63) == 0) tred[tid >> 6] = l;
    __syncthreads();
    if (tid == 0) {
        float bs = tred[0] + tred[1] + tred[2] + tred[3];
        int slot = (idx < 16384) ? (8 + (b & 7)) : (b & 7);
        atomicAdd(ws + SLOT + 32 * slot, bs);
    }
    __syncthreads();   // vmcnt(0): slot atomic completed before counter RMW
    if (tid == 0) {
        int last = 0;
        int o1 = __hip_atomic_fetch_add((int*)(ws + CTR_L1 + 32 * (b & 7)), 1,
                                        __ATOMIC_RELAXED, __HIP_MEMORY_SCOPE_AGENT);
        if (o1 == 23) {
            int o2 = __hip_atomic_fetch_add((int*)(ws + CTR_L2), 1,
                                            __ATOMIC_RELAXED, __HIP_MEMORY_SCOPE_AGENT);
            last = (o2 == 7);
        }
        lastf = last;
    }
    __syncthreads();
    if (!lastf) return;

    if (tid < 64) {                      // lane-parallel final combine
        float v2 = 0.0f;
        if (tid < 26) {
            float x = __hip_atomic_load(ws + SLOT + 32 * tid, __ATOMIC_RELAXED, __HIP_MEMORY_SCOPE_AGENT);
            float wgt;
            if (tid < 8)       wgt = 1.0f / 8192.0f;             // c-log
            else if (tid < 24) wgt = 1.0f / 4096.0f;             // t-log + ortho
            else if (tid == 24) wgt = -2.0f * INV_T / 8192.0f;   // posC
            else                wgt = -INV_T / 4096.0f;          // posT
            v2 = x * wgt;
        }
        #pragma unroll
        for (int m = 1; m < 64; m <<= 1) v2 += __shfl_xor(v2, m);
        if (tid == 0) out[0] = v2 + 8.0f * INV_T;   // 32768*INV_T/8192 + 16384*INV_T/4096
    }
}

extern "C" void kernel_launch(void* const* d_in, const int* in_sizes, int n_in,
                              void* d_out, int out_size, void* d_ws, size_t ws_size,
                              hipStream_t stream) {
    (void)in_sizes; (void)n_in; (void)out_size; (void)ws_size;
    const float* in0 = (const float*)d_in[0];
    const float* in1 = (const float*)d_in[1];
    const float* in2 = (const float*)d_in[2];
    const float* in3 = (const float*)d_in[3];
    float* ws = (float*)d_ws;
    float* out = (float*)d_out;

    hipLaunchKernelGGL(k_prep, dim3(512), dim3(256), 0, stream, in0, in1, in2, in3, ws);
    hipLaunchKernelGGL(k_gram, dim3(3456), dim3(256), 0, stream, ws);
    hipLaunchKernelGGL(k_tail, dim3(NBLK_TAIL), dim3(256), 0, stream, ws, out);
}

// Round 10
// 131.358 us; speedup vs baseline: 1.1637x; 1.1637x over previous
//
#include <hip/hip_runtime.h>
#include <math.h>

// CMCV3Loss: B=512, S=8, D=128, H=64. Inputs: 4 x (4096x128 fp32), seq_len.
// bf16-MFMA symmetric grams; loss_row = lse_{m!=n} - pos. Fixed max-shift:
// ex = exp((s-1)*INV_T) = exp2(fma(s, C1EXP, -C1EXP)) since s<=1 for normalized vecs.
// 3 launches: k_prep, k_gram, k_tail.
// R10: FRAGMENT-MAJOR storage. k_prep writes bf16 planes pre-arranged so a
// wave's MFMA fragment load is one contiguous 1KB global access:
//   zf'[input][g=row>>4][kc 0..15][row&15][8]          (temporal, full-norm)
//   zh'[input][p][g=b>>4][hc 0..15][b&15][8]           (contrastive; hc 0-7 sh-norm, 8-15 pv-norm)
// k_gram K-loop: direct global->VGPR loads (no LDS, no barriers). R9's failure
// (16-row scatter per load) is fixed; R8's barrier-drain stalls are gone.
//
// ws float offsets:
#define CTR_L1 0        // 8 counters, stride 32 floats (k_tail arrival)
#define CTR_L2 2048     // single second-level counter
#define RS_T   49152    // temporal rowsums [4][4096]
#define RS_C   65536    // contrastive rowsums [4 calls][8 p][1024]
#define SLOT   98304    // slots stride 32: 0..7 c-log, 8..15 t-log, 16..23 ortho, 24 posC, 25 posT
// ws byte offsets (bf16 arrays):
#define ZF_BYTE 397312   // zf' fragment-major [4][256][16][16][8]
#define ZH_BYTE 4591616  // zh' fragment-major [4][8][32][16][16][8]

#define INV_T 14.285714285714286f
#define C1EXP 20.609929155556627f   // INV_T * log2(e)
#define EPS_N 1e-8f
#define NBLK_TAIL 192                // 8 groups x 24

typedef __attribute__((ext_vector_type(8))) short short8;
typedef __attribute__((ext_vector_type(4))) float floatx4;

__device__ __forceinline__ const float* pick4(const float* a, const float* b,
                                              const float* c, const float* d, int i) {
    return i == 0 ? a : i == 1 ? b : i == 2 ? c : d;
}

__device__ __forceinline__ unsigned short f2bf(float x) {
    unsigned u = __float_as_uint(x);
    u += 0x7fff + ((u >> 16) & 1);
    return (unsigned short)(u >> 16);
}

// ---------- prep: zero counters+RS, per-sequence norms, fragment-major bf16 convert, small dots ----------
// grid 512 (one per sequence s; rows s*8..s*8+7 of each input), block 256.
__global__ __launch_bounds__(256) void k_prep(const float* __restrict__ in0, const float* __restrict__ in1,
                                              const float* __restrict__ in2, const float* __restrict__ in3,
                                              float* __restrict__ ws) {
    __shared__ float buf[4][8][128];
    __shared__ float iv[3][32];         // [sh,pv,full], idx = input*8+row
    __shared__ float red[3];
    const int s = blockIdx.x;
    const int tid = threadIdx.x;

    int gid = s * 256 + tid;
    if (gid < 2080) ws[gid] = 0.0f;                 // arrival counters
    if (gid < 50176) ws[RS_T + gid] = 0.0f;         // rowsums + slots
    if (tid < 3) red[tid] = 0.0f;

    #pragma unroll
    for (int i = 0; i < 4; i++) {
        int e4 = tid + i * 256;
        int inp = e4 >> 8, row = (e4 >> 5) & 7, c4 = e4 & 31;
        float4 f = *(const float4*)(pick4(in0, in1, in2, in3, inp) + (size_t)(s * 8 + row) * 128 + c4 * 4);
        *(float4*)(&buf[inp][row][c4 * 4]) = f;
    }
    __syncthreads();

    // norms
    {
        int row32 = tid >> 3, seg = tid & 7;
        const float* rp_ = &buf[row32 >> 3][row32 & 7][seg * 16];
        float ss = 0.0f;
        #pragma unroll
        for (int k = 0; k < 4; k++) {
            float4 x = *(const float4*)(rp_ + k * 4);
            ss = fmaf(x.x, x.x, fmaf(x.y, x.y, fmaf(x.z, x.z, fmaf(x.w, x.w, ss))));
        }
        ss += __shfl_xor(ss, 1); ss += __shfl_xor(ss, 2);
        float cross = __shfl_xor(ss, 4);
        if (seg == 0) {
            iv[0][row32] = 1.0f / fmaxf(sqrtf(ss), EPS_N);
            iv[2][row32] = 1.0f / fmaxf(sqrtf(ss + cross), EPS_N);
        }
        if (seg == 4) iv[1][row32] = 1.0f / fmaxf(sqrtf(ss), EPS_N);
    }
    __syncthreads();

    // fragment-major convert: thread = input(t>>6) x row((t>>3)&7) x 2 k-chunks ((t&7)*2)
    // temporal plane: row rg = s*8+row -> group rg>>4, slot rg&15
    // contrastive plane: p = row (since rg&7==row), b = s -> group s>>4, slot s&15
    {
        int input = tid >> 6, row = (tid >> 3) & 7, kc0 = (tid & 7) * 2;
        int rg = s * 8 + row;
        float scF = iv[2][input * 8 + row];
        unsigned short* zf = (unsigned short*)((char*)ws + ZF_BYTE) + (size_t)input * 524288
                           + ((rg >> 4) * 16) * 128 + (rg & 15) * 8;
        unsigned short* zh = (unsigned short*)((char*)ws + ZH_BYTE) + (size_t)input * 524288
                           + row * 65536 + ((s >> 4) * 16) * 128 + (s & 15) * 8;
        #pragma unroll
        for (int kk = 0; kk < 2; kk++) {
            int kc = kc0 + kk;
            float scH = iv[kc < 8 ? 0 : 1][input * 8 + row];
            const float* bp = &buf[input][row][kc * 8];
            float4 x = *(const float4*)bp;
            float4 y = *(const float4*)(bp + 4);
            ushort4 f0, f1, h0, h1;
            f0.x = f2bf(x.x * scF); f0.y = f2bf(x.y * scF); f0.z = f2bf(x.z * scF); f0.w = f2bf(x.w * scF);
            f1.x = f2bf(y.x * scF); f1.y = f2bf(y.y * scF); f1.z = f2bf(y.z * scF); f1.w = f2bf(y.w * scF);
            h0.x = f2bf(x.x * scH); h0.y = f2bf(x.y * scH); h0.z = f2bf(x.z * scH); h0.w = f2bf(x.w * scH);
            h1.x = f2bf(y.x * scH); h1.y = f2bf(y.y * scH); h1.z = f2bf(y.z * scH); h1.w = f2bf(y.w * scH);
            *(ushort4*)(zf + kc * 128)     = f0;
            *(ushort4*)(zf + kc * 128 + 4) = f1;
            *(ushort4*)(zh + kc * 128)     = h0;
            *(ushort4*)(zh + kc * 128 + 4) = h1;
        }
    }

    // small dots: ortho (tid<48), contrastive pos (48..79), temporal pos (80..135)
    float val = 0.0f;
    int cat = -1;
    if (tid < 48) {
        const int oa[6]  = {0, 2, 1, 3, 0, 1};
        const int oaf[6] = {0, 0, 0, 0, 64, 64};
        const int ob[6]  = {0, 2, 1, 3, 2, 3};
        int term = tid >> 3, row = tid & 7;
        const float* A = &buf[oa[term]][row][oaf[term]];
        const float* B = &buf[ob[term]][row][64];
        float d = 0.0f;
        #pragma unroll
        for (int k = 0; k < 16; k++) {
            float4 x = *(const float4*)(A + k * 4);
            float4 y = *(const float4*)(B + k * 4);
            d = fmaf(x.x, y.x, fmaf(x.y, y.y, fmaf(x.z, y.z, fmaf(x.w, y.w, d))));
        }
        float ia = iv[oaf[term] ? 1 : 0][oa[term] * 8 + row];
        float ib = iv[1][ob[term] * 8 + row];
        val = fmaxf(d * ia * ib, 0.0f);
        cat = 2;
    } else if (tid < 80) {
        const int ca[4] = {0, 1, 0, 2}, cb[4] = {2, 3, 1, 3}, coff[4] = {0, 0, 64, 64};
        int call = (tid - 48) >> 3, row = (tid - 48) & 7;
        const float* A = &buf[ca[call]][row][coff[call]];
        const float* B = &buf[cb[call]][row][coff[call]];
        float d = 0.0f;
        #pragma unroll
        for (int k = 0; k < 16; k++) {
            float4 x = *(const float4*)(A + k * 4);
            float4 y = *(const float4*)(B + k * 4);
            d = fmaf(x.x, y.x, fmaf(x.y, y.y, fmaf(x.z, y.z, fmaf(x.w, y.w, d))));
        }
        int ivb = coff[call] ? 1 : 0;
        val = d * iv[ivb][ca[call] * 8 + row] * iv[ivb][cb[call] * 8 + row];
        cat = 0;
    } else if (tid < 136) {
        int u = tid - 80;
        int inp = u / 14, v = u % 14, pp = v >> 1, half = v & 1;
        int ra = (pp == 0) ? 1 : (pp + 1);
        const float* A = &buf[inp][ra][half * 64];
        const float* B = &buf[inp][0][half * 64];
        float d = 0.0f;
        #pragma unroll
        for (int k = 0; k < 16; k++) {
            float4 x = *(const float4*)(A + k * 4);
            float4 y = *(const float4*)(B + k * 4);
            d = fmaf(x.x, y.x, fmaf(x.y, y.y, fmaf(x.z, y.z, fmaf(x.w, y.w, d))));
        }
        float wgt = (pp == 0) ? 2.0f : 1.0f;
        val = d * wgt * iv[2][inp * 8 + ra] * iv[2][inp * 8];
        cat = 1;
    }
    if (cat >= 0) atomicAdd(&red[cat], val);
    __syncthreads();
    if (tid == 0) atomicAdd(ws + SLOT + 32 * 24, red[0]);
    if (tid == 1) atomicAdd(ws + SLOT + 32 * 25, red[1]);
    if (tid == 2) atomicAdd(ws + SLOT + 32 * (16 + (s & 7)), red[2]);
}

// ---------- unified symmetric gram: coalesced direct global->VGPR fragment loads ----------
// blocks [0,2176) temporal (4 inputs x 544), [2176,3456) contrastive (32 x 40)
// Frag load: base + (lane>>4)*256B + (lane&15)*16B = contiguous 1KB per wave.
__global__ __launch_bounds__(256, 4) void k_gram(float* __restrict__ ws) {
    const int tid = threadIdx.x;
    const int b = blockIdx.x;
    const int w = tid >> 6, lane = tid & 63, quad = (tid >> 4) & 3, l15 = tid & 15;
    const int wrow = (w >> 1) * 64, wcol = (w & 1) * 64;
    const int laneoff = (lane >> 4) * 128 + (lane & 15) * 8;   // shorts

    const short* aPtr;
    const short* bPtr;
    int nk;
    float* rsR;
    float* rsC;
    bool diag;

    if (b < 2176) {
        int input = b / 544, t = b % 544;
        int j = t >> 5, i = t & 31;
        if (j == 16 && i >= 16) return;          // folded duplicate
        int rt = i, ct = (i + j) & 31;
        diag = (j == 0);
        const short* zf = (const short*)((const char*)ws + ZF_BYTE) + (size_t)input * 524288;
        aPtr = zf + (rt * 8 + (wrow >> 4)) * 2048 + laneoff;
        bPtr = zf + (ct * 8 + (wcol >> 4)) * 2048 + laneoff;
        nk = 2;
        rsR = ws + RS_T + input * 4096 + rt * 128;
        rsC = ws + RS_T + input * 4096 + ct * 128;
    } else {
        int c = b - 2176;
        int callp = c / 40, t = c % 40;
        int j = t >> 3, i = t & 7;
        if (j == 4 && i >= 4) return;
        int call = callp >> 3, p = callp & 7;
        int rt = i, ct = (i + j) & 7;
        diag = (j == 0);
        const int ca[4] = {0, 1, 0, 2}, cb[4] = {2, 3, 1, 3};
        const int hb = (call >= 2) ? 8 : 0;      // sh chunks 0-7, pv chunks 8-15
        const short* zh = (const short*)((const char*)ws + ZH_BYTE);
        int rbase = rt * 128, cbase = ct * 128;
        aPtr = zh + (size_t)(rbase < 512 ? ca[call] : cb[call]) * 524288 + p * 65536
                  + ((((rbase & 511) >> 4) + (wrow >> 4)) * 16 + hb) * 128 + laneoff;
        bPtr = zh + (size_t)(cbase < 512 ? ca[call] : cb[call]) * 524288 + p * 65536
                  + ((((cbase & 511) >> 4) + (wcol >> 4)) * 16 + hb) * 128 + laneoff;
        nk = 1;
        rsR = ws + RS_C + (call * 8 + p) * 1024 + rbase;
        rsC = ws + RS_C + (call * 8 + p) * 1024 + cbase;
    }

    floatx4 acc[4][4];
    #pragma unroll
    for (int ri = 0; ri < 4; ri++)
        #pragma unroll
        for (int ci = 0; ci < 4; ci++) acc[ri][ci] = (floatx4){0.f, 0.f, 0.f, 0.f};

    for (int kh = 0; kh < nk; kh++) {
        #pragma unroll
        for (int ks = 0; ks < 2; ks++) {
            const int koff = (kh * 8 + ks * 4) * 128;     // k-chunk (quad folded into laneoff)
            short8 a[4], bb[4];
            #pragma unroll
            for (int i = 0; i < 4; i++) {
                a[i]  = *(const short8*)(aPtr + i * 2048 + koff);
                bb[i] = *(const short8*)(bPtr + i * 2048 + koff);
            }
            #pragma unroll
            for (int ri = 0; ri < 4; ri++)
                #pragma unroll
                for (int ci = 0; ci < 4; ci++)
                    acc[ri][ci] = __builtin_amdgcn_mfma_f32_16x16x32_bf16(a[ri], bb[ci], acc[ri][ci], 0, 0, 0);
        }
    }

    if (diag) {
        #pragma unroll
        for (int ri = 0; ri < 4; ri++) {
            #pragma unroll
            for (int reg = 0; reg < 4; reg++) {
                int rloc = wrow + ri * 16 + quad * 4 + reg;
                float rp = 0.f;
                #pragma unroll
                for (int ci = 0; ci < 4; ci++) {
                    int cloc = wcol + ci * 16 + l15;
                    float ex = __builtin_amdgcn_exp2f(fmaf(acc[ri][ci][reg], C1EXP, -C1EXP));
                    rp += (cloc != rloc) ? ex : 0.f;   // exact diag exclusion
                }
                rp += __shfl_xor(rp, 1); rp += __shfl_xor(rp, 2);
                rp += __shfl_xor(rp, 4); rp += __shfl_xor(rp, 8);
                if (l15 == 0) atomicAdd(rsR + rloc, rp);
            }
        }
    } else {
        float colp[4] = {0.f, 0.f, 0.f, 0.f};
        #pragma unroll
        for (int ri = 0; ri < 4; ri++) {
            #pragma unroll
            for (int reg = 0; reg < 4; reg++) {
                int rloc = wrow + ri * 16 + quad * 4 + reg;
                float rp = 0.f;
                #pragma unroll
                for (int ci = 0; ci < 4; ci++) {
                    float ex = __builtin_amdgcn_exp2f(fmaf(acc[ri][ci][reg], C1EXP, -C1EXP));
                    rp += ex;
                    colp[ci] += ex;
                }
                rp += __shfl_xor(rp, 1); rp += __shfl_xor(rp, 2);
                rp += __shfl_xor(rp, 4); rp += __shfl_xor(rp, 8);
                if (l15 == 0) atomicAdd(rsR + rloc, rp);
            }
        }
        #pragma unroll
        for (int ci = 0; ci < 4; ci++) {           // transpose contribution
            colp[ci] += __shfl_xor(colp[ci], 16);
            colp[ci] += __shfl_xor(colp[ci], 32);
            if (lane < 16) atomicAdd(rsC + wcol + ci * 16 + l15, colp[ci]);
        }
    }
}

// ---------- tail: grid-parallel logsum + arrival-gated final ----------
__global__ __launch_bounds__(256) void k_tail(float* __restrict__ ws, float* __restrict__ out) {
    __shared__ float tred[4];
    __shared__ int lastf;
    const int tid = threadIdx.x;
    const int b = blockIdx.x;
    const int idx = b * 256 + tid;       // blocks 0..63 temporal, 64..191 contrastive

    float l = __logf(ws[RS_T + idx]);
    #pragma unroll
    for (int m = 1; m < 64; m <<= 1) l += __shfl_xor(l, m);
    if ((tid & 63) == 0) tred[tid >> 6] = l;
    __syncthreads();
    if (tid == 0) {
        float bs = tred[0] + tred[1] + tred[2] + tred[3];
        int slot = (idx < 16384) ? (8 + (b & 7)) : (b & 7);
        atomicAdd(ws + SLOT + 32 * slot, bs);
    }
    __syncthreads();   // vmcnt(0): slot atomic completed before counter RMW
    if (tid == 0) {
        int last = 0;
        int o1 = __hip_atomic_fetch_add((int*)(ws + CTR_L1 + 32 * (b & 7)), 1,
                                        __ATOMIC_RELAXED, __HIP_MEMORY_SCOPE_AGENT);
        if (o1 == 23) {
            int o2 = __hip_atomic_fetch_add((int*)(ws + CTR_L2), 1,
                                            __ATOMIC_RELAXED, __HIP_MEMORY_SCOPE_AGENT);
            last = (o2 == 7);
        }
        lastf = last;
    }
    __syncthreads();
    if (!lastf) return;

    if (tid < 64) {                      // lane-parallel final combine
        float v2 = 0.0f;
        if (tid < 26) {
            float x = __hip_atomic_load(ws + SLOT + 32 * tid, __ATOMIC_RELAXED, __HIP_MEMORY_SCOPE_AGENT);
            float wgt;
            if (tid < 8)       wgt = 1.0f / 8192.0f;             // c-log
            else if (tid < 24) wgt = 1.0f / 4096.0f;             // t-log + ortho
            else if (tid == 24) wgt = -2.0f * INV_T / 8192.0f;   // posC
            else                wgt = -INV_T / 4096.0f;          // posT
            v2 = x * wgt;
        }
        #pragma unroll
        for (int m = 1; m < 64; m <<= 1) v2 += __shfl_xor(v2, m);
        if (tid == 0) out[0] = v2 + 8.0f * INV_T;   // 32768*INV_T/8192 + 16384*INV_T/4096
    }
}

extern "C" void kernel_launch(void* const* d_in, const int* in_sizes, int n_in,
                              void* d_out, int out_size, void* d_ws, size_t ws_size,
                              hipStream_t stream) {
    (void)in_sizes; (void)n_in; (void)out_size; (void)ws_size;
    const float* in0 = (const float*)d_in[0];
    const float* in1 = (const float*)d_in[1];
    const float* in2 = (const float*)d_in[2];
    const float* in3 = (const float*)d_in[3];
    float* ws = (float*)d_ws;
    float* out = (float*)d_out;

    hipLaunchKernelGGL(k_prep, dim3(512), dim3(256), 0, stream, in0, in1, in2, in3, ws);
    hipLaunchKernelGGL(k_gram, dim3(3456), dim3(256), 0, stream, ws);
    hipLaunchKernelGGL(k_tail, dim3(NBLK_TAIL), dim3(256), 0, stream, ws, out);
}

// Round 11
// 116.335 us; speedup vs baseline: 1.3140x; 1.1291x over previous
//
#include <hip/hip_runtime.h>
#include <math.h>

// CMCV3Loss: B=512, S=8, D=128, H=64. Inputs: 4 x (4096x128 fp32), seq_len.
// bf16-MFMA symmetric grams; loss_row = lse_{m!=n} - pos. Fixed max-shift:
// ex = exp((s-1)*INV_T) = exp2(fma(s, C1EXP, -C1EXP)) since s<=1 for normalized vecs.
// 3 launches: k_prep, k_gram, k_tail.
// R11: (a) k_prep convert blocks write FULL LINES (block = input x 16-seq group,
// owns contiguous zf/zh regions; R10's 8B cross-block scatter caused ~46MB of
// write-allocate/false-sharing traffic). (b) k_gram multi-tile blocks: row-sums
// accumulate in registers across column tiles (row atomics 1M -> 82K, no
// per-tile row shuffles); loads of tile t+1 overlap epilogue of tile t.
//
// ws float offsets:
#define CTR_L1 0        // 8 counters, stride 32 floats (k_tail arrival)
#define CTR_L2 2048     // single second-level counter
#define RS_T   49152    // temporal rowsums [4][4096]
#define RS_C   65536    // contrastive rowsums [4 calls][8 p][1024]
#define SLOT   98304    // slots stride 32: 0..7 c-log, 8..15 t-log, 16..23 ortho, 24 posC, 25 posT
// ws byte offsets (bf16 arrays, fragment-major):
#define ZF_BYTE 397312   // zf [4 input][256 g][16 kc][16 slot][8]   row = g*16+slot
#define ZH_BYTE 4591616  // zh [4 input][8 p][32 g][16 kc][16 slot][8]  b = g*16+slot; kc<8 sh-norm, >=8 pv-norm

#define INV_T 14.285714285714286f
#define C1EXP 20.609929155556627f   // INV_T * log2(e)
#define EPS_N 1e-8f
#define NBLK_TAIL 192                // 8 groups x 24

typedef __attribute__((ext_vector_type(8))) short short8;
typedef __attribute__((ext_vector_type(4))) float floatx4;

__device__ __forceinline__ const float* pick4(const float* a, const float* b,
                                              const float* c, const float* d, int i) {
    return i == 0 ? a : i == 1 ? b : i == 2 ? c : d;
}

__device__ __forceinline__ unsigned short f2bf(float x) {
    unsigned u = __float_as_uint(x);
    u += 0x7fff + ((u >> 16) & 1);
    return (unsigned short)(u >> 16);
}

__device__ __forceinline__ ushort4 cvt4(float4 x, float sc) {
    ushort4 o;
    o.x = f2bf(x.x * sc); o.y = f2bf(x.y * sc); o.z = f2bf(x.z * sc); o.w = f2bf(x.w * sc);
    return o;
}

// ---------- prep: blocks 0..127 = fragment-major convert (full-line writes);
//                  blocks 128..639 = per-sequence dots + zeroing ----------
__global__ __launch_bounds__(256) void k_prep(const float* __restrict__ in0, const float* __restrict__ in1,
                                              const float* __restrict__ in2, const float* __restrict__ in3,
                                              float* __restrict__ ws) {
    __shared__ float ivf[128], ivs[128], ivp[128];   // convert branch
    __shared__ float buf[4][8][128];                 // dots branch
    __shared__ float iv[3][32];
    __shared__ float red[3];
    const int tid = threadIdx.x;
    const int blk = blockIdx.x;

    if (blk < 128) {
        // ---- convert: input x group of 16 sequences (128 rows) ----
        const int input = blk >> 5, g = blk & 31;
        const float* src = pick4(in0, in1, in2, in3, input) + (size_t)(g * 128) * 128;
        {   // norms: 2 threads per row (half = 64 cols each)
            int r = tid >> 1, half = tid & 1;
            const float* rp_ = src + r * 128 + half * 64;
            float ss = 0.0f;
            #pragma unroll
            for (int k = 0; k < 16; k++) {
                float4 x = *(const float4*)(rp_ + k * 4);
                ss = fmaf(x.x, x.x, fmaf(x.y, x.y, fmaf(x.z, x.z, fmaf(x.w, x.w, ss))));
            }
            float other = __shfl_xor(ss, 1);
            if (half == 0) {
                ivs[r] = 1.0f / fmaxf(sqrtf(ss), EPS_N);
                ivf[r] = 1.0f / fmaxf(sqrtf(ss + other), EPS_N);
            } else {
                ivp[r] = 1.0f / fmaxf(sqrtf(ss), EPS_N);
            }
        }
        __syncthreads();
        unsigned short* zf = (unsigned short*)((char*)ws + ZF_BYTE) + (size_t)input * 524288 + (size_t)g * 16384;
        unsigned short* zh = (unsigned short*)((char*)ws + ZH_BYTE) + (size_t)input * 524288;
        #pragma unroll
        for (int k = 0; k < 8; k++) {            // zf: 2048 16B chunks, coalesced
            int ch = k * 256 + tid;              // [gg:3][kc:4][slot:4]
            int lr = ((ch >> 8) << 4) | (ch & 15);
            int kc = (ch >> 4) & 15;
            const float* sp = src + lr * 128 + kc * 8;
            float sc = ivf[lr];
            *(ushort4*)(zf + ch * 8)     = cvt4(*(const float4*)sp, sc);
            *(ushort4*)(zf + ch * 8 + 4) = cvt4(*(const float4*)(sp + 4), sc);
        }
        #pragma unroll
        for (int k = 0; k < 8; k++) {            // zh: 2048 16B chunks, coalesced per p-region
            int ch = k * 256 + tid;              // [p:3][kc:4][slot:4]
            int p = ch >> 8, kc = (ch >> 4) & 15, slot = ch & 15;
            int lr = slot * 8 + p;
            const float* sp = src + lr * 128 + kc * 8;
            float sc = (kc < 8 ? ivs : ivp)[lr];
            unsigned short* dst = zh + (size_t)p * 65536 + (size_t)g * 2048 + (ch & 255) * 8;
            *(ushort4*)dst       = cvt4(*(const float4*)sp, sc);
            *(ushort4*)(dst + 4) = cvt4(*(const float4*)(sp + 4), sc);
        }
        return;
    }

    // ---- dots + zeroing: one block per sequence ----
    const int s = blk - 128;
    int gid = s * 256 + tid;
    if (gid < 2080) ws[gid] = 0.0f;                 // arrival counters
    if (gid < 50176) ws[RS_T + gid] = 0.0f;         // rowsums + slots
    if (tid < 3) red[tid] = 0.0f;

    #pragma unroll
    for (int i = 0; i < 4; i++) {
        int e4 = tid + i * 256;
        int inp = e4 >> 8, row = (e4 >> 5) & 7, c4 = e4 & 31;
        float4 f = *(const float4*)(pick4(in0, in1, in2, in3, inp) + (size_t)(s * 8 + row) * 128 + c4 * 4);
        *(float4*)(&buf[inp][row][c4 * 4]) = f;
    }
    __syncthreads();
    {
        int row32 = tid >> 3, seg = tid & 7;
        const float* rp_ = &buf[row32 >> 3][row32 & 7][seg * 16];
        float ss = 0.0f;
        #pragma unroll
        for (int k = 0; k < 4; k++) {
            float4 x = *(const float4*)(rp_ + k * 4);
            ss = fmaf(x.x, x.x, fmaf(x.y, x.y, fmaf(x.z, x.z, fmaf(x.w, x.w, ss))));
        }
        ss += __shfl_xor(ss, 1); ss += __shfl_xor(ss, 2);
        float cross = __shfl_xor(ss, 4);
        if (seg == 0) {
            iv[0][row32] = 1.0f / fmaxf(sqrtf(ss), EPS_N);
            iv[2][row32] = 1.0f / fmaxf(sqrtf(ss + cross), EPS_N);
        }
        if (seg == 4) iv[1][row32] = 1.0f / fmaxf(sqrtf(ss), EPS_N);
    }
    __syncthreads();

    float val = 0.0f;
    int cat = -1;
    if (tid < 48) {
        const int oa[6]  = {0, 2, 1, 3, 0, 1};
        const int oaf[6] = {0, 0, 0, 0, 64, 64};
        const int ob[6]  = {0, 2, 1, 3, 2, 3};
        int term = tid >> 3, row = tid & 7;
        const float* A = &buf[oa[term]][row][oaf[term]];
        const float* B = &buf[ob[term]][row][64];
        float d = 0.0f;
        #pragma unroll
        for (int k = 0; k < 16; k++) {
            float4 x = *(const float4*)(A + k * 4);
            float4 y = *(const float4*)(B + k * 4);
            d = fmaf(x.x, y.x, fmaf(x.y, y.y, fmaf(x.z, y.z, fmaf(x.w, y.w, d))));
        }
        float ia = iv[oaf[term] ? 1 : 0][oa[term] * 8 + row];
        float ib = iv[1][ob[term] * 8 + row];
        val = fmaxf(d * ia * ib, 0.0f);
        cat = 2;
    } else if (tid < 80) {
        const int ca[4] = {0, 1, 0, 2}, cb[4] = {2, 3, 1, 3}, coff[4] = {0, 0, 64, 64};
        int call = (tid - 48) >> 3, row = (tid - 48) & 7;
        const float* A = &buf[ca[call]][row][coff[call]];
        const float* B = &buf[cb[call]][row][coff[call]];
        float d = 0.0f;
        #pragma unroll
        for (int k = 0; k < 16; k++) {
            float4 x = *(const float4*)(A + k * 4);
            float4 y = *(const float4*)(B + k * 4);
            d = fmaf(x.x, y.x, fmaf(x.y, y.y, fmaf(x.z, y.z, fmaf(x.w, y.w, d))));
        }
        int ivb = coff[call] ? 1 : 0;
        val = d * iv[ivb][ca[call] * 8 + row] * iv[ivb][cb[call] * 8 + row];
        cat = 0;
    } else if (tid < 136) {
        int u = tid - 80;
        int inp = u / 14, v = u % 14, pp = v >> 1, half = v & 1;
        int ra = (pp == 0) ? 1 : (pp + 1);
        const float* A = &buf[inp][ra][half * 64];
        const float* B = &buf[inp][0][half * 64];
        float d = 0.0f;
        #pragma unroll
        for (int k = 0; k < 16; k++) {
            float4 x = *(const float4*)(A + k * 4);
            float4 y = *(const float4*)(B + k * 4);
            d = fmaf(x.x, y.x, fmaf(x.y, y.y, fmaf(x.z, y.z, fmaf(x.w, y.w, d))));
        }
        float wgt = (pp == 0) ? 2.0f : 1.0f;
        val = d * wgt * iv[2][inp * 8 + ra] * iv[2][inp * 8];
        cat = 1;
    }
    if (cat >= 0) atomicAdd(&red[cat], val);
    __syncthreads();
    if (tid == 0) atomicAdd(ws + SLOT + 32 * 24, red[0]);
    if (tid == 1) atomicAdd(ws + SLOT + 32 * 25, red[1]);
    if (tid == 2) atomicAdd(ws + SLOT + 32 * (16 + (s & 7)), red[2]);
}

// ---------- multi-tile symmetric gram: direct coalesced frag loads, register rowsums ----------
// blocks [0,1024): temporal — input = b>>8, rt = (b>>3)&31, chunk = b&7:
//   j in {2*chunk, 2*chunk+1} (+ j=16 when chunk==7 && rt<16). j=0 is the diag tile.
// blocks [1024,1280): contrastive — c = b-1024: call = c>>6, p = (c>>3)&7, rt = c&7:
//   j in 0..3 (+ j=4 when rt<4).
__global__ __launch_bounds__(256, 3) void k_gram(float* __restrict__ ws) {
    const int tid = threadIdx.x;
    const int b = blockIdx.x;
    const int w = tid >> 6, lane = tid & 63, quad = (tid >> 4) & 3, l15 = tid & 15;
    const int wrow = (w >> 1) * 64, wcol = (w & 1) * 64;
    const int laneoff = (lane >> 4) * 128 + (lane & 15) * 8;   // shorts

    const short* aPtr;
    const short* planeA;     // for bPtr computation per ct
    const short* planeB;
    int nk, ntiles, jbase, modm;
    float* rsR;
    float* rsCbase;
    bool temporal = (b < 1024);
    int rt;

    if (temporal) {
        int input = b >> 8;
        rt = (b >> 3) & 31;
        int chunk = b & 7;
        const short* zf = (const short*)((const char*)ws + ZF_BYTE) + (size_t)input * 524288;
        planeA = planeB = zf;
        aPtr = zf + (rt * 8 + (wrow >> 4)) * 2048 + laneoff;
        nk = 2; modm = 31;
        jbase = chunk * 2;
        ntiles = 2 + ((chunk == 7 && rt < 16) ? 1 : 0);
        rsR = ws + RS_T + input * 4096 + rt * 128;
        rsCbase = ws + RS_T + input * 4096;
    } else {
        int c = b - 1024;
        int call = c >> 6, p = (c >> 3) & 7;
        rt = c & 7;
        const int ca[4] = {0, 1, 0, 2}, cb[4] = {2, 3, 1, 3};
        const int hb = (call >= 2) ? 8 : 0;
        const short* zh = (const short*)((const char*)ws + ZH_BYTE);
        planeA = zh + (size_t)ca[call] * 524288 + (size_t)p * 65536 + hb * 128;
        planeB = zh + (size_t)cb[call] * 524288 + (size_t)p * 65536 + hb * 128;
        const short* rpl = (rt < 4) ? planeA : planeB;
        aPtr = rpl + ((rt & 3) * 8 + (wrow >> 4)) * 2048 + laneoff;
        nk = 1; modm = 7;
        jbase = 0;
        ntiles = (rt < 4) ? 5 : 4;
        rsR = ws + RS_C + (call * 8 + p) * 1024 + rt * 128;
        rsCbase = ws + RS_C + (call * 8 + p) * 1024;
    }

    float rp_acc[16];
    #pragma unroll
    for (int i = 0; i < 16; i++) rp_acc[i] = 0.0f;

    for (int t = 0; t < ntiles; t++) {
        int j = (temporal && t == 2) ? 16 : (jbase + t);
        int ct = (rt + j) & modm;
        bool diag = (j == 0);
        const short* bPtr;
        if (temporal) {
            bPtr = planeA + (ct * 8 + (wcol >> 4)) * 2048 + laneoff;
        } else {
            const short* cpl = (ct < 4) ? planeA : planeB;
            bPtr = cpl + ((ct & 3) * 8 + (wcol >> 4)) * 2048 + laneoff;
        }

        floatx4 acc[4][4];
        #pragma unroll
        for (int ri = 0; ri < 4; ri++)
            #pragma unroll
            for (int ci = 0; ci < 4; ci++) acc[ri][ci] = (floatx4){0.f, 0.f, 0.f, 0.f};

        for (int ksb = 0; ksb < 2 * nk; ksb++) {
            const int koff = ksb * 512;
            short8 a[4], bb[4];
            #pragma unroll
            for (int i = 0; i < 4; i++) {
                a[i]  = *(const short8*)(aPtr + i * 2048 + koff);
                bb[i] = *(const short8*)(bPtr + i * 2048 + koff);
            }
            #pragma unroll
            for (int ri = 0; ri < 4; ri++)
                #pragma unroll
                for (int ci = 0; ci < 4; ci++)
                    acc[ri][ci] = __builtin_amdgcn_mfma_f32_16x16x32_bf16(a[ri], bb[ci], acc[ri][ci], 0, 0, 0);
        }

        if (diag) {
            #pragma unroll
            for (int ri = 0; ri < 4; ri++) {
                #pragma unroll
                for (int reg = 0; reg < 4; reg++) {
                    int rloc = wrow + ri * 16 + quad * 4 + reg;
                    float rp = 0.f;
                    #pragma unroll
                    for (int ci = 0; ci < 4; ci++) {
                        int cloc = wcol + ci * 16 + l15;
                        float ex = __builtin_amdgcn_exp2f(fmaf(acc[ri][ci][reg], C1EXP, -C1EXP));
                        rp += (cloc != rloc) ? ex : 0.f;   // exact diag exclusion
                    }
                    rp_acc[ri * 4 + reg] += rp;
                }
            }
        } else {
            float colp[4] = {0.f, 0.f, 0.f, 0.f};
            #pragma unroll
            for (int ri = 0; ri < 4; ri++) {
                #pragma unroll
                for (int reg = 0; reg < 4; reg++) {
                    float rp = 0.f;
                    #pragma unroll
                    for (int ci = 0; ci < 4; ci++) {
                        float ex = __builtin_amdgcn_exp2f(fmaf(acc[ri][ci][reg], C1EXP, -C1EXP));
                        rp += ex;
                        colp[ci] += ex;
                    }
                    rp_acc[ri * 4 + reg] += rp;
                }
            }
            float* rsC = rsCbase + ct * 128;
            #pragma unroll
            for (int ci = 0; ci < 4; ci++) {           // transpose contribution (per tile)
                colp[ci] += __shfl_xor(colp[ci], 16);
                colp[ci] += __shfl_xor(colp[ci], 32);
                if (lane < 16) atomicAdd(rsC + wcol + ci * 16 + l15, colp[ci]);
            }
        }
    }

    // row-sum flush: once per block
    #pragma unroll
    for (int ri = 0; ri < 4; ri++) {
        #pragma unroll
        for (int reg = 0; reg < 4; reg++) {
            float rp = rp_acc[ri * 4 + reg];
            rp += __shfl_xor(rp, 1); rp += __shfl_xor(rp, 2);
            rp += __shfl_xor(rp, 4); rp += __shfl_xor(rp, 8);
            if (l15 == 0) atomicAdd(rsR + wrow + ri * 16 + quad * 4 + reg, rp);
        }
    }
}

// ---------- tail: grid-parallel logsum + arrival-gated final ----------
__global__ __launch_bounds__(256) void k_tail(float* __restrict__ ws, float* __restrict__ out) {
    __shared__ float tred[4];
    __shared__ int lastf;
    const int tid = threadIdx.x;
    const int b = blockIdx.x;
    const int idx = b * 256 + tid;       // blocks 0..63 temporal, 64..191 contrastive

    float l = __logf(ws[RS_T + idx]);
    #pragma unroll
    for (int m = 1; m < 64; m <<= 1) l += __shfl_xor(l, m);
    if ((tid & 63) == 0) tred[tid >> 6] = l;
    __syncthreads();
    if (tid == 0) {
        float bs = tred[0] + tred[1] + tred[2] + tred[3];
        int slot = (idx < 16384) ? (8 + (b & 7)) : (b & 7);
        atomicAdd(ws + SLOT + 32 * slot, bs);
    }
    __syncthreads();   // vmcnt(0): slot atomic completed before counter RMW
    if (tid == 0) {
        int last = 0;
        int o1 = __hip_atomic_fetch_add((int*)(ws + CTR_L1 + 32 * (b & 7)), 1,
                                        __ATOMIC_RELAXED, __HIP_MEMORY_SCOPE_AGENT);
        if (o1 == 23) {
            int o2 = __hip_atomic_fetch_add((int*)(ws + CTR_L2), 1,
                                            __ATOMIC_RELAXED, __HIP_MEMORY_SCOPE_AGENT);
            last = (o2 == 7);
        }
        lastf = last;
    }
    __syncthreads();
    if (!lastf) return;

    if (tid < 64) {                      // lane-parallel final combine
        float v2 = 0.0f;
        if (tid < 26) {
            float x = __hip_atomic_load(ws + SLOT + 32 * tid, __ATOMIC_RELAXED, __HIP_MEMORY_SCOPE_AGENT);
            float wgt;
            if (tid < 8)       wgt = 1.0f / 8192.0f;             // c-log
            else if (tid < 24) wgt = 1.0f / 4096.0f;             // t-log + ortho
            else if (tid == 24) wgt = -2.0f * INV_T / 8192.0f;   // posC
            else                wgt = -INV_T / 4096.0f;          // posT
            v2 = x * wgt;
        }
        #pragma unroll
        for (int m = 1; m < 64; m <<= 1) v2 += __shfl_xor(v2, m);
        if (tid == 0) out[0] = v2 + 8.0f * INV_T;   // 32768*INV_T/8192 + 16384*INV_T/4096
    }
}

extern "C" void kernel_launch(void* const* d_in, const int* in_sizes, int n_in,
                              void* d_out, int out_size, void* d_ws, size_t ws_size,
                              hipStream_t stream) {
    (void)in_sizes; (void)n_in; (void)out_size; (void)ws_size;
    const float* in0 = (const float*)d_in[0];
    const float* in1 = (const float*)d_in[1];
    const float* in2 = (const float*)d_in[2];
    const float* in3 = (const float*)d_in[3];
    float* ws = (float*)d_ws;
    float* out = (float*)d_out;

    hipLaunchKernelGGL(k_prep, dim3(640), dim3(256), 0, stream, in0, in1, in2, in3, ws);
    hipLaunchKernelGGL(k_gram, dim3(1280), dim3(256), 0, stream, ws);
    hipLaunchKernelGGL(k_tail, dim3(NBLK_TAIL), dim3(256), 0, stream, ws, out);
}